// Round 14
// baseline (113.732 us; speedup 1.0000x reference)
//
#include <hip/hip_runtime.h>
#include <math.h>

#define DIMC 512
#define HW 4096
#define SCALE 0.125f
#define EPSN 1e-12f

typedef __attribute__((ext_vector_type(8))) short bf16x8;
typedef __attribute__((ext_vector_type(4))) float f32x4;

__device__ __forceinline__ unsigned short f2bf(float f) {
    union { float f; unsigned int u; } v; v.f = f;
    unsigned int u = v.u;
    return (unsigned short)((u + 0x7fffu + ((u >> 16) & 1u)) >> 16);
}
__device__ __forceinline__ float bf2f(unsigned short h) {
    union { unsigned int u; float f; } v; v.u = ((unsigned int)h) << 16;
    return v.f;
}

union Pack8 { int4 v; unsigned short u[8]; };

__device__ __forceinline__ void gload_lds16(const unsigned short* src, char* ldst) {
    __builtin_amdgcn_global_load_lds(
        (const __attribute__((address_space(1))) void*)src,
        (__attribute__((address_space(3))) void*)ldst, 16, 0, 0);
}

// ---------------------------------------------------------------------------
// P1 (all prep merged): blocks 0..511   : Wq,Wk -> Wb bf16
//                       blocks 512..575 : WvT = bf16(Wv^T)
//                       blocks 576..831 : Wp -> Wpb bf16
//                       blocks 832..4927: prep_x (xT + xmb)
// ---------------------------------------------------------------------------
__global__ __launch_bounds__(256) void prep_wx(
    const float* __restrict__ Wq, const float* __restrict__ Wk,
    const float* __restrict__ Wv, const float* __restrict__ Wp,
    const float* __restrict__ x, const float* __restrict__ mask,
    unsigned short* __restrict__ Wb, unsigned short* __restrict__ WvT,
    unsigned short* __restrict__ Wpb,
    unsigned short* __restrict__ xT, unsigned short* __restrict__ xmb)
{
    const int blk = blockIdx.x;
    const int t = threadIdx.x;
    if (blk < 512) {
        int i = (blk * 256 + t) * 4;
        const float* s = (i < 262144) ? Wq : Wk;
        int off = i & 262143;
        float4 v4 = *(const float4*)(s + off);
        ushort4 o;
        o.x = f2bf(v4.x); o.y = f2bf(v4.y); o.z = f2bf(v4.z); o.w = f2bf(v4.w);
        *(ushort4*)(Wb + i) = o;
    } else if (blk < 576) {
        const int bb = blk - 512;
        const int cp0 = (bb >> 3) * 64;
        const int c30 = (bb & 7) * 64;
        __shared__ unsigned short sT[64][65];
        #pragma unroll
        for (int i = 0; i < 4; ++i) {
            int ch = t + i * 256;
            int r = ch >> 4, col4 = (ch & 15) * 4;
            float4 v4 = *(const float4*)(Wv + (size_t)(cp0 + r) * DIMC + c30 + col4);
            sT[r][col4 + 0] = f2bf(v4.x); sT[r][col4 + 1] = f2bf(v4.y);
            sT[r][col4 + 2] = f2bf(v4.z); sT[r][col4 + 3] = f2bf(v4.w);
        }
        __syncthreads();
        #pragma unroll
        for (int i = 0; i < 2; ++i) {
            int ch = t + i * 256;
            int n = ch >> 3, cc = (ch & 7) * 8;
            Pack8 pk;
            #pragma unroll
            for (int e = 0; e < 8; ++e) pk.u[e] = sT[cc + e][n];
            *(int4*)(WvT + (size_t)(c30 + n) * DIMC + cp0 + cc) = pk.v;
        }
    } else if (blk < 832) {
        int i = ((blk - 576) * 256 + t) * 4;
        float4 v4 = *(const float4*)(Wp + i);
        ushort4 o;
        o.x = f2bf(v4.x); o.y = f2bf(v4.y); o.z = f2bf(v4.z); o.w = f2bf(v4.w);
        *(ushort4*)(Wpb + i) = o;
    } else {
        const int idx = blk - 832;
        const int n0 = (idx & 63) * 64;
        const int c0 = ((idx >> 6) & 7) * 64;
        const int b  = idx >> 9;
        __shared__ unsigned short sT[64][65];
        #pragma unroll
        for (int i = 0; i < 4; ++i) {
            int ch = t + i * 256;
            int r = ch >> 4, col4 = (ch & 15) * 4;
            float4 v4 = *(const float4*)(x + ((size_t)b * DIMC + c0 + r) * HW + n0 + col4);
            sT[r][col4 + 0] = f2bf(v4.x); sT[r][col4 + 1] = f2bf(v4.y);
            sT[r][col4 + 2] = f2bf(v4.z); sT[r][col4 + 3] = f2bf(v4.w);
            float4 mv = *(const float4*)(mask + (size_t)b * HW + n0 + col4);
            ushort4 xm;
            xm.x = f2bf(v4.x * mv.x); xm.y = f2bf(v4.y * mv.y);
            xm.z = f2bf(v4.z * mv.z); xm.w = f2bf(v4.w * mv.w);
            *(ushort4*)(xmb + ((size_t)b * DIMC + c0 + r) * HW + n0 + col4) = xm;
        }
        __syncthreads();
        #pragma unroll
        for (int i = 0; i < 2; ++i) {
            int ch = t + i * 256;
            int n = ch >> 3, cc = (ch & 7) * 8;
            Pack8 pk;
            #pragma unroll
            for (int e = 0; e < 8; ++e) pk.u[e] = sT[cc + e][n];
            *(int4*)(xT + ((size_t)b * HW + n0 + n) * DIMC + c0 + cc) = pk.v;
        }
    }
}

// ---------------------------------------------------------------------------
// K1: TRIANGULAR Gram GEMM, split-K, XCD-grouped.
// ---------------------------------------------------------------------------
__global__ __launch_bounds__(256) void gram_mfma(
    const unsigned short* __restrict__ xmb, unsigned short* __restrict__ Gpart)
{
    const int f = blockIdx.x;            // 0..319
    const int r8 = f & 7, q = f >> 3;
    const int pair = q >> 2;
    const int grp  = r8 + ((q & 3) << 3);
    const int b  = grp & 7;
    const int sp = grp >> 3;
    const int TA[10] = {0,0,0,0,1,1,1,2,2,3};
    const int TB[10] = {0,1,2,3,1,2,3,2,3,3};
    const int cA0 = TA[pair] * 128;
    const int cB0 = TB[pair] * 128;
    const unsigned short* A = xmb + (size_t)b * DIMC * HW + (size_t)cA0 * HW + sp * 1024;
    const unsigned short* B = xmb + (size_t)b * DIMC * HW + (size_t)cB0 * HW + sp * 1024;

    __shared__ __align__(16) char sm[65536];

    const int t = threadIdx.x, lane = t & 63, w = t >> 6;
    const int wm = w >> 1, wn = w & 1;
    const int rsub = lane >> 3;
    const int srccol = ((lane & 7) ^ rsub) << 3;

    f32x4 zero = {0.f, 0.f, 0.f, 0.f};
    f32x4 acc[4][4];
    #pragma unroll
    for (int m = 0; m < 4; ++m)
        #pragma unroll
        for (int n = 0; n < 4; ++n) acc[m][n] = zero;

    #define STAGE_G(buf, c0)                                                  \
        {                                                                     \
            char* dst = sm + (buf) * 32768;                                   \
            _Pragma("unroll")                                                 \
            for (int i = 0; i < 4; ++i) {                                     \
                int ii = w * 4 + i;                                           \
                gload_lds16(A + (size_t)(ii * 8 + rsub) * HW + (c0) + srccol, \
                            dst + ii * 1024);                                 \
                gload_lds16(B + (size_t)(ii * 8 + rsub) * HW + (c0) + srccol, \
                            dst + 16384 + ii * 1024);                         \
            }                                                                 \
        }

    STAGE_G(0, 0);
    int cur = 0;
    for (int c0 = 0; c0 < 1024; c0 += 64) {
        __syncthreads();
        if (c0 + 64 < 1024) STAGE_G(cur ^ 1, c0 + 64);
        const char* sA = sm + cur * 32768;
        const char* sB = sA + 16384;
        #pragma unroll
        for (int s = 0; s < 2; ++s) {
            bf16x8 af[4], bfr[4];
            #pragma unroll
            for (int m = 0; m < 4; ++m) {
                int r = wm * 64 + m * 16 + (lane & 15);
                int byte = r * 128 + s * 64 + ((lane >> 4) << 4);
                byte ^= (r & 7) << 4;
                af[m] = *(const bf16x8*)(sA + byte);
            }
            #pragma unroll
            for (int n = 0; n < 4; ++n) {
                int r = wn * 64 + n * 16 + (lane & 15);
                int byte = r * 128 + s * 64 + ((lane >> 4) << 4);
                byte ^= (r & 7) << 4;
                bfr[n] = *(const bf16x8*)(sB + byte);
            }
            #pragma unroll
            for (int m = 0; m < 4; ++m)
                #pragma unroll
                for (int n = 0; n < 4; ++n)
                    acc[m][n] = __builtin_amdgcn_mfma_f32_16x16x32_bf16(
                        af[m], bfr[n], acc[m][n], 0, 0, 0);
        }
        cur ^= 1;
    }
    #undef STAGE_G

    unsigned short* st = (unsigned short*)sm;
    __syncthreads();
    #pragma unroll
    for (int m = 0; m < 4; ++m)
        #pragma unroll
        for (int n = 0; n < 4; ++n)
            #pragma unroll
            for (int r4 = 0; r4 < 4; ++r4) {
                int jl = wm * 64 + m * 16 + ((lane >> 4) << 2) + r4;
                int nl = wn * 64 + n * 16 + (lane & 15);
                st[jl * 136 + nl] = f2bf(acc[m][n][r4]);
            }
    __syncthreads();
    unsigned short* Gp = Gpart + ((size_t)(sp * 8 + b) * 10 + pair) * 16384;
    #pragma unroll
    for (int it = 0; it < 8; ++it) {
        int idx = t + it * 256, jl = idx >> 4, l16 = idx & 15;
        int4 pv = *(int4*)((char*)sm + jl * 272 + l16 * 16);
        *(int4*)(Gp + (size_t)jl * 128 + l16 * 8) = pv;
    }
}

// ---------------------------------------------------------------------------
// K1b: reduce 4 split partials -> G, tile + transposed mirror.
// ---------------------------------------------------------------------------
__global__ __launch_bounds__(256) void gram_reduce_sym(
    const unsigned short* __restrict__ Gpart, unsigned short* __restrict__ G)
{
    const int pair = blockIdx.x;
    const int b    = blockIdx.y;
    const int TA[10] = {0,0,0,0,1,1,1,2,2,3};
    const int TB[10] = {0,1,2,3,1,2,3,2,3,3};
    const int ta = TA[pair], tb = TB[pair];
    const int t = threadIdx.x;

    __shared__ unsigned short sT[128][130];
    unsigned short* Gb = G + (size_t)b * DIMC * DIMC;

    #pragma unroll
    for (int ch = 0; ch < 8; ++ch) {
        int e = ch * 2048 + t * 8;
        int i = e >> 7, j = e & 127;
        Pack8 p0, p1, p2, p3, o;
        p0.v = *(const int4*)(Gpart + ((size_t)(0 * 8 + b) * 10 + pair) * 16384 + e);
        p1.v = *(const int4*)(Gpart + ((size_t)(1 * 8 + b) * 10 + pair) * 16384 + e);
        p2.v = *(const int4*)(Gpart + ((size_t)(2 * 8 + b) * 10 + pair) * 16384 + e);
        p3.v = *(const int4*)(Gpart + ((size_t)(3 * 8 + b) * 10 + pair) * 16384 + e);
        #pragma unroll
        for (int k = 0; k < 8; ++k) {
            unsigned short s = f2bf(bf2f(p0.u[k]) + bf2f(p1.u[k]) + bf2f(p2.u[k]) + bf2f(p3.u[k]));
            o.u[k] = s;
            sT[i][j + k] = s;
        }
        *(int4*)(Gb + (size_t)(ta * 128 + i) * DIMC + tb * 128 + j) = o.v;
    }
    if (ta != tb) {
        __syncthreads();
        #pragma unroll
        for (int ch = 0; ch < 8; ++ch) {
            int e = ch * 2048 + t * 8;
            int i2 = e >> 7, j2 = e & 127;
            Pack8 o;
            #pragma unroll
            for (int k = 0; k < 8; ++k) o.u[k] = sT[j2 + k][i2];
            *(int4*)(Gb + (size_t)(tb * 128 + i2) * DIMC + ta * 128 + j2) = o.v;
        }
    }
}

// ---------------------------------------------------------------------------
// K2: generic 128x128 NT GEMM, K=512, row stride 512, bf16 out.
// R14: 1D grid, b = f&7 (b-grouped for XCD L2: G[b]/operands = 4 MB = one L2)
// grid = nj*nn*8; inner = f>>3: n0t = inner % nn, j0t = inner / nn.
// ---------------------------------------------------------------------------
__global__ __launch_bounds__(256) void gemm_nn_128(
    const unsigned short* __restrict__ Ag, size_t aBatch,
    const unsigned short* __restrict__ Bg, size_t bBatch,
    unsigned short* __restrict__ Cg, size_t cBatch, int nn)
{
    const int f = blockIdx.x;
    const int b = f & 7;
    const int inner = f >> 3;
    const int j0 = (inner / nn) * 128;
    const int n0 = (inner % nn) * 128;
    const unsigned short* A = Ag + (size_t)b * aBatch + (size_t)j0 * DIMC;
    const unsigned short* B = Bg + (size_t)b * bBatch + (size_t)n0 * DIMC;

    __shared__ __align__(16) char sm[65536];

    const int t = threadIdx.x, lane = t & 63, w = t >> 6;
    const int wm = w >> 1, wn = w & 1;
    const int rsub = lane >> 3;
    const int srccol = ((lane & 7) ^ rsub) << 3;

    f32x4 zero = {0.f, 0.f, 0.f, 0.f};
    f32x4 acc[4][4];
    #pragma unroll
    for (int m = 0; m < 4; ++m)
        #pragma unroll
        for (int n = 0; n < 4; ++n) acc[m][n] = zero;

    #define STAGE_NN(buf, c0)                                                   \
        {                                                                       \
            char* dst = sm + (buf) * 32768;                                     \
            _Pragma("unroll")                                                   \
            for (int i = 0; i < 4; ++i) {                                       \
                int ii = w * 4 + i;                                             \
                gload_lds16(A + (size_t)(ii * 8 + rsub) * DIMC + (c0) + srccol, \
                            dst + ii * 1024);                                   \
                gload_lds16(B + (size_t)(ii * 8 + rsub) * DIMC + (c0) + srccol, \
                            dst + 16384 + ii * 1024);                           \
            }                                                                   \
        }

    STAGE_NN(0, 0);
    int cur = 0;
    for (int c0 = 0; c0 < DIMC; c0 += 64) {
        __syncthreads();
        if (c0 + 64 < DIMC) STAGE_NN(cur ^ 1, c0 + 64);
        const char* sA = sm + cur * 32768;
        const char* sB = sA + 16384;
        #pragma unroll
        for (int s = 0; s < 2; ++s) {
            bf16x8 af[4], bfr[4];
            #pragma unroll
            for (int m = 0; m < 4; ++m) {
                int r = wm * 64 + m * 16 + (lane & 15);
                int byte = r * 128 + s * 64 + ((lane >> 4) << 4);
                byte ^= (r & 7) << 4;
                af[m] = *(const bf16x8*)(sA + byte);
            }
            #pragma unroll
            for (int n = 0; n < 4; ++n) {
                int r = wn * 64 + n * 16 + (lane & 15);
                int byte = r * 128 + s * 64 + ((lane >> 4) << 4);
                byte ^= (r & 7) << 4;
                bfr[n] = *(const bf16x8*)(sB + byte);
            }
            #pragma unroll
            for (int m = 0; m < 4; ++m)
                #pragma unroll
                for (int n = 0; n < 4; ++n)
                    acc[m][n] = __builtin_amdgcn_mfma_f32_16x16x32_bf16(
                        af[m], bfr[n], acc[m][n], 0, 0, 0);
        }
        cur ^= 1;
    }
    #undef STAGE_NN

    unsigned short* st = (unsigned short*)sm;
    __syncthreads();
    #pragma unroll
    for (int m = 0; m < 4; ++m)
        #pragma unroll
        for (int n = 0; n < 4; ++n)
            #pragma unroll
            for (int r4 = 0; r4 < 4; ++r4) {
                int jl = wm * 64 + m * 16 + ((lane >> 4) << 2) + r4;
                int nl = wn * 64 + n * 16 + (lane & 15);
                st[jl * 136 + nl] = f2bf(acc[m][n][r4]);
            }
    __syncthreads();
    #pragma unroll
    for (int it = 0; it < 8; ++it) {
        int idx = t + it * 256, jl = idx >> 4, l16 = idx & 15;
        int4 pv = *(int4*)((char*)sm + jl * 272 + l16 * 16);
        *(int4*)(Cg + (size_t)b * cBatch + (size_t)(j0 + jl) * DIMC + n0 + l16 * 8) = pv;
    }
}

// ---------------------------------------------------------------------------
// K4 (R14 FUSED): rsq row-dots + S GEMM + softmax + Wp2 MFMA, per (b,h).
// Softmax result written into swizzled LDS (same layout STAGE produces), then
// 4 j-tiles of Wp2[b][jt*128..][h*64..+64] computed in-block.
// ---------------------------------------------------------------------------
__global__ __launch_bounds__(256) void s_softmax_wp2(
    const unsigned short* __restrict__ TU, const unsigned short* __restrict__ Wb,
    const unsigned short* __restrict__ Wpb, unsigned short* __restrict__ Wp2b)
{
    const int bh = blockIdx.x;
    const int b = bh >> 3, h = bh & 7;
    const unsigned short* A = TU + ((size_t)b * 1024 + h * 64) * DIMC;
    const unsigned short* B = Wb + 262144 + (size_t)(h * 64) * DIMC;

    __shared__ __align__(16) char sm[32768];
    __shared__ float sS[64][65];
    __shared__ float srq[64];
    __shared__ float srk[64];
    __shared__ __align__(16) unsigned short aSwz[4096];   // swizzled attnT [d][c]

    const int t = threadIdx.x, lane = t & 63, w = t >> 6;
    const int wm = w >> 1, wn = w & 1;
    const int rsub = lane >> 3;
    const int srccol = ((lane & 7) ^ rsub) << 3;

    // ---- fused row-dots for rsq ----
    {
        const int rid  = t >> 1;
        const int half = t & 1;
        const int isK  = (rid >= 64);
        const int rl   = rid & 63;
        const unsigned short* ar = TU + ((size_t)b * 1024 + (isK ? 512 : 0) + h * 64 + rl) * DIMC
                                 + half * 256;
        const unsigned short* wr = Wb + (isK ? 262144 : 0) + (size_t)(h * 64 + rl) * DIMC
                                 + half * 256;
        float s = 0.f;
        #pragma unroll 8
        for (int i = 0; i < 32; ++i) {
            Pack8 pa, pw;
            pa.v = *(const int4*)(ar + i * 8);
            pw.v = *(const int4*)(wr + i * 8);
            #pragma unroll
            for (int e = 0; e < 8; ++e) s = fmaf(bf2f(pa.u[e]), bf2f(pw.u[e]), s);
        }
        s += __shfl_xor(s, 1, 2);
        if (half == 0) {
            float r = 1.0f / fmaxf(sqrtf(s), EPSN);
            if (isK) srk[rl] = r; else srq[rl] = r;
        }
    }

    // ---- S = T x Wk^T (64x64, K=512) ----
    f32x4 zero = {0.f, 0.f, 0.f, 0.f};
    f32x4 acc[2][2];
    #pragma unroll
    for (int m = 0; m < 2; ++m)
        #pragma unroll
        for (int n = 0; n < 2; ++n) acc[m][n] = zero;

    #define STAGE_S(buf, c0)                                                    \
        {                                                                       \
            char* dst = sm + (buf) * 16384;                                     \
            _Pragma("unroll")                                                   \
            for (int i = 0; i < 2; ++i) {                                       \
                int ii = w * 2 + i;                                             \
                gload_lds16(A + (size_t)(ii * 8 + rsub) * DIMC + (c0) + srccol, \
                            dst + ii * 1024);                                   \
                gload_lds16(B + (size_t)(ii * 8 + rsub) * DIMC + (c0) + srccol, \
                            dst + 8192 + ii * 1024);                            \
            }                                                                   \
        }

    STAGE_S(0, 0);
    int cur = 0;
    for (int c0 = 0; c0 < DIMC; c0 += 64) {
        __syncthreads();
        if (c0 + 64 < DIMC) STAGE_S(cur ^ 1, c0 + 64);
        const char* sA = sm + cur * 16384;
        const char* sB = sA + 8192;
        #pragma unroll
        for (int s = 0; s < 2; ++s) {
            bf16x8 aq[2], bk[2];
            #pragma unroll
            for (int m = 0; m < 2; ++m) {
                int r = wm * 32 + m * 16 + (lane & 15);
                int byte = r * 128 + s * 64 + ((lane >> 4) << 4);
                byte ^= (r & 7) << 4;
                aq[m] = *(const bf16x8*)(sA + byte);
            }
            #pragma unroll
            for (int n = 0; n < 2; ++n) {
                int r = wn * 32 + n * 16 + (lane & 15);
                int byte = r * 128 + s * 64 + ((lane >> 4) << 4);
                byte ^= (r & 7) << 4;
                bk[n] = *(const bf16x8*)(sB + byte);
            }
            #pragma unroll
            for (int m = 0; m < 2; ++m)
                #pragma unroll
                for (int n = 0; n < 2; ++n)
                    acc[m][n] = __builtin_amdgcn_mfma_f32_16x16x32_bf16(
                        aq[m], bk[n], acc[m][n], 0, 0, 0);
        }
        cur ^= 1;
    }
    #undef STAGE_S

    #pragma unroll
    for (int m = 0; m < 2; ++m)
        #pragma unroll
        for (int n = 0; n < 2; ++n)
            #pragma unroll
            for (int r4 = 0; r4 < 4; ++r4) {
                int r = wm * 32 + m * 16 + ((lane >> 4) << 2) + r4;
                int c = wn * 32 + n * 16 + (lane & 15);
                sS[r][c] = acc[m][n][r4];
            }
    __syncthreads();

    // ---- softmax; write into swizzled aSwz[d][c] (attn row r == c-index) ----
    {
        const int r = t >> 2;
        const int p = t & 3;
        const float rq = srq[r];
        float row[16];
        #pragma unroll
        for (int c = 0; c < 16; ++c)
            row[c] = sS[r][p * 16 + c] * SCALE * rq * srk[p * 16 + c];
        float mx = row[0];
        #pragma unroll
        for (int c = 1; c < 16; ++c) mx = fmaxf(mx, row[c]);
        mx = fmaxf(mx, __shfl_xor(mx, 1, 4));
        mx = fmaxf(mx, __shfl_xor(mx, 2, 4));
        float sum = 0.f;
        #pragma unroll
        for (int c = 0; c < 16; ++c) { row[c] = __expf(row[c] - mx); sum += row[c]; }
        sum += __shfl_xor(sum, 1, 4);
        sum += __shfl_xor(sum, 2, 4);
        const float inv = 1.0f / sum;
        // element (d = p*16+i, c = r); swizzled elem idx within row:
        //   ((c>>3) ^ (d&7))*8 + (c&7)
        #pragma unroll
        for (int i = 0; i < 16; ++i) {
            int d = p * 16 + i;
            int ei = (((r >> 3) ^ (d & 7)) << 3) + (r & 7);
            aSwz[d * 64 + ei] = f2bf(row[i] * inv);
        }
    }
    __syncthreads();

    // ---- Wp2 tiles: for jt: C[j][d] = sum_c Wpb[j][h*64+c] * attn[c][d] ----
    for (int jt = 0; jt < 4; ++jt) {
        const unsigned short* Ap = Wpb + (size_t)(jt * 128) * DIMC + h * 64;
        #pragma unroll
        for (int i = 0; i < 4; ++i) {
            int ii = w * 4 + i;   // 16 chunks x 8 rows = 128 j-rows
            gload_lds16(Ap + (size_t)(ii * 8 + rsub) * DIMC + srccol, sm + ii * 1024);
        }
        __syncthreads();

        f32x4 acc2[2][4];
        #pragma unroll
        for (int m = 0; m < 2; ++m)
            #pragma unroll
            for (int n = 0; n < 4; ++n) acc2[m][n] = zero;

        #pragma unroll
        for (int s = 0; s < 2; ++s) {
            bf16x8 af[2], bfr[4];
            #pragma unroll
            for (int m = 0; m < 2; ++m) {
                int r = w * 32 + m * 16 + (lane & 15);
                int byte = r * 128 + s * 64 + ((lane >> 4) << 4);
                byte ^= (r & 7) << 4;
                af[m] = *(const bf16x8*)(sm + byte);
            }
            #pragma unroll
            for (int n = 0; n < 4; ++n) {
                int r = n * 16 + (lane & 15);
                int byte = r * 128 + s * 64 + ((lane >> 4) << 4);
                byte ^= (r & 7) << 4;
                bfr[n] = *(const bf16x8*)((const char*)aSwz + byte);
            }
            #pragma unroll
            for (int m = 0; m < 2; ++m)
                #pragma unroll
                for (int n = 0; n < 4; ++n)
                    acc2[m][n] = __builtin_amdgcn_mfma_f32_16x16x32_bf16(
                        af[m], bfr[n], acc2[m][n], 0, 0, 0);
        }
        __syncthreads();   // MFMA done; safe to overwrite sm with epilogue

        unsigned short* st = (unsigned short*)sm;
        #pragma unroll
        for (int m = 0; m < 2; ++m)
            #pragma unroll
            for (int n = 0; n < 4; ++n)
                #pragma unroll
                for (int r4 = 0; r4 < 4; ++r4) {
                    int jl = w * 32 + m * 16 + ((lane >> 4) << 2) + r4;
                    int dl = n * 16 + (lane & 15);
                    st[jl * 72 + dl] = f2bf(acc2[m][n][r4]);
                }
        __syncthreads();
        #pragma unroll
        for (int it = 0; it < 4; ++it) {
            int idx = t + it * 256, jl = idx >> 3, ch = idx & 7;
            int4 pv = *(int4*)((char*)sm + jl * 144 + ch * 16);
            *(int4*)(Wp2b + ((size_t)b * DIMC + jt * 128 + jl) * DIMC + h * 64 + ch * 8) = pv;
        }
        __syncthreads();   // before next jt's staging overwrites sm
    }
}

// ---------------------------------------------------------------------------
// K6: final GEMM, XCD-grouped: out[b][j][n] = sum_c3 Wfb[j][c3]*xT[n][c3]
// ---------------------------------------------------------------------------
__global__ __launch_bounds__(256) void final_mfma(
    const unsigned short* __restrict__ Wfb, const unsigned short* __restrict__ xT,
    float* __restrict__ out)
{
    const int f = blockIdx.x;            // 0..1023
    const int r8 = f & 7, q = f >> 3;
    const int jt = q & 3;
    const int nt = r8 + (((q >> 2) & 3) << 3);
    const int b  = q >> 4;
    const int j0 = jt * 128;
    const int n0 = nt * 128;
    const unsigned short* A = Wfb + (size_t)b * DIMC * DIMC + (size_t)j0 * DIMC;
    const unsigned short* B = xT + (size_t)b * HW * DIMC + (size_t)n0 * DIMC;

    __shared__ __align__(16) char sm[65536];

    const int t = threadIdx.x, lane = t & 63, w = t >> 6;
    const int wm = w >> 1, wn = w & 1;
    const int rsub = lane >> 3;
    const int srccol = ((lane & 7) ^ rsub) << 3;

    f32x4 zero = {0.f, 0.f, 0.f, 0.f};
    f32x4 acc[4][4];
    #pragma unroll
    for (int m = 0; m < 4; ++m)
        #pragma unroll
        for (int n = 0; n < 4; ++n) acc[m][n] = zero;

    #define STAGE_FIN(buf, c0)                                                  \
        {                                                                       \
            char* dst = sm + (buf) * 32768;                                     \
            _Pragma("unroll")                                                   \
            for (int i = 0; i < 4; ++i) {                                       \
                int ii = w * 4 + i;                                             \
                gload_lds16(A + (size_t)(ii * 8 + rsub) * DIMC + (c0) + srccol, \
                            dst + ii * 1024);                                   \
                gload_lds16(B + (size_t)(ii * 8 + rsub) * DIMC + (c0) + srccol, \
                            dst + 16384 + ii * 1024);                           \
            }                                                                   \
        }

    STAGE_FIN(0, 0);
    int cur = 0;
    for (int c0 = 0; c0 < DIMC; c0 += 64) {
        __syncthreads();
        if (c0 + 64 < DIMC) STAGE_FIN(cur ^ 1, c0 + 64);
        const char* sA = sm + cur * 32768;
        const char* sB = sA + 16384;
        #pragma unroll
        for (int s = 0; s < 2; ++s) {
            bf16x8 af[4], bfr[4];
            #pragma unroll
            for (int m = 0; m < 4; ++m) {
                int r = wm * 64 + m * 16 + (lane & 15);
                int byte = r * 128 + s * 64 + ((lane >> 4) << 4);
                byte ^= (r & 7) << 4;
                af[m] = *(const bf16x8*)(sA + byte);
            }
            #pragma unroll
            for (int n = 0; n < 4; ++n) {
                int r = wn * 64 + n * 16 + (lane & 15);
                int byte = r * 128 + s * 64 + ((lane >> 4) << 4);
                byte ^= (r & 7) << 4;
                bfr[n] = *(const bf16x8*)(sB + byte);
            }
            #pragma unroll
            for (int m = 0; m < 4; ++m)
                #pragma unroll
                for (int n = 0; n < 4; ++n)
                    acc[m][n] = __builtin_amdgcn_mfma_f32_16x16x32_bf16(
                        af[m], bfr[n], acc[m][n], 0, 0, 0);
        }
        cur ^= 1;
    }
    #undef STAGE_FIN

    #pragma unroll
    for (int m = 0; m < 4; ++m)
        #pragma unroll
        for (int r4 = 0; r4 < 4; ++r4) {
            int j = j0 + wm * 64 + m * 16 + ((lane >> 4) << 2) + r4;
            size_t rowbase = ((size_t)b * DIMC + j) * HW + n0 + wn * 64 + (lane & 15);
            #pragma unroll
            for (int n = 0; n < 4; ++n)
                out[rowbase + n * 16] = acc[m][n][r4];
        }
}

// ---------------------------------------------------------------------------
// Workspace (bytes):
//   xT    @ 0           67,108,864
//   xmb   @ 67108864    67,108,864
//   Wb    @ 134217728    1,048,576
//   WvT   @ 135266304      524,288
//   Wpb   @ 135790592      524,288
//   G     @ 136314880    4,194,304
//   TU    @ 140509184    8,388,608
//   Wp2b  @ 149422080    4,194,304
//   Wfb   @ 153616384    4,194,304
//   Gpart @ 157810688   10,485,760
// ---------------------------------------------------------------------------
extern "C" void kernel_launch(void* const* d_in, const int* in_sizes, int n_in,
                              void* d_out, int out_size, void* d_ws, size_t ws_size,
                              hipStream_t stream)
{
    const float* x    = (const float*)d_in[0];
    const float* mask = (const float*)d_in[1];
    const float* Wq   = (const float*)d_in[2];
    const float* Wk   = (const float*)d_in[3];
    const float* Wv   = (const float*)d_in[4];
    const float* Wp   = (const float*)d_in[5];
    float* out = (float*)d_out;
    char* wsb = (char*)d_ws;

    unsigned short* xT   = (unsigned short*)(wsb + 0);
    unsigned short* xmb  = (unsigned short*)(wsb + 67108864);
    unsigned short* Wb   = (unsigned short*)(wsb + 134217728);
    unsigned short* WvT  = (unsigned short*)(wsb + 135266304);
    unsigned short* Wpb  = (unsigned short*)(wsb + 135790592);
    unsigned short* G    = (unsigned short*)(wsb + 136314880);
    unsigned short* TU   = (unsigned short*)(wsb + 140509184);
    unsigned short* Wp2b = (unsigned short*)(wsb + 149422080);
    unsigned short* Wfb  = (unsigned short*)(wsb + 153616384);
    unsigned short* Gpart= (unsigned short*)(wsb + 157810688);

    prep_wx        <<<4928,            256, 0, stream>>>(Wq, Wk, Wv, Wp, x, mask,
                                                         Wb, WvT, Wpb, xT, xmb);
    gram_mfma      <<<320,             256, 0, stream>>>(xmb, Gpart);
    gram_reduce_sym<<<dim3(10, 8),     256, 0, stream>>>(Gpart, G);
    // TU[b] = [Wq|Wk] (1024x512) * G[b]; grid = 4nn*8jt*8b, b-grouped
    gemm_nn_128    <<<256,             256, 0, stream>>>(Wb, (size_t)0, G, (size_t)(DIMC*DIMC), TU, (size_t)(1024*DIMC), 4);
    s_softmax_wp2  <<<64,              256, 0, stream>>>(TU, Wb, Wpb, Wp2b);
    // Wfb[b] = Wp2b[b] * WvT; grid = 4nn*4jt*8b, b-grouped
    gemm_nn_128    <<<128,             256, 0, stream>>>(Wp2b, (size_t)(DIMC*DIMC), WvT, (size_t)0, Wfb, (size_t)(DIMC*DIMC), 4);
    final_mfma     <<<1024,            256, 0, stream>>>(Wfb, xT, out);
}

// Round 15
// 112.227 us; speedup vs baseline: 1.0134x; 1.0134x over previous
//
#include <hip/hip_runtime.h>
#include <math.h>

#define DIMC 512
#define HW 4096
#define SCALE 0.125f
#define EPSN 1e-12f

typedef __attribute__((ext_vector_type(8))) short bf16x8;
typedef __attribute__((ext_vector_type(4))) float f32x4;

__device__ __forceinline__ unsigned short f2bf(float f) {
    union { float f; unsigned int u; } v; v.f = f;
    unsigned int u = v.u;
    return (unsigned short)((u + 0x7fffu + ((u >> 16) & 1u)) >> 16);
}
__device__ __forceinline__ float bf2f(unsigned short h) {
    union { unsigned int u; float f; } v; v.u = ((unsigned int)h) << 16;
    return v.f;
}

union Pack8 { int4 v; unsigned short u[8]; };

__device__ __forceinline__ void gload_lds16(const unsigned short* src, char* ldst) {
    __builtin_amdgcn_global_load_lds(
        (const __attribute__((address_space(1))) void*)src,
        (__attribute__((address_space(3))) void*)ldst, 16, 0, 0);
}

// ---------------------------------------------------------------------------
// P1 (all prep merged): blocks 0..511   : Wq,Wk -> Wb bf16
//                       blocks 512..575 : WvT = bf16(Wv^T)
//                       blocks 576..831 : Wp -> Wpb bf16
//                       blocks 832..4927: prep_x (xT + xmb)
// ---------------------------------------------------------------------------
__global__ __launch_bounds__(256) void prep_wx(
    const float* __restrict__ Wq, const float* __restrict__ Wk,
    const float* __restrict__ Wv, const float* __restrict__ Wp,
    const float* __restrict__ x, const float* __restrict__ mask,
    unsigned short* __restrict__ Wb, unsigned short* __restrict__ WvT,
    unsigned short* __restrict__ Wpb,
    unsigned short* __restrict__ xT, unsigned short* __restrict__ xmb)
{
    const int blk = blockIdx.x;
    const int t = threadIdx.x;
    if (blk < 512) {
        int i = (blk * 256 + t) * 4;
        const float* s = (i < 262144) ? Wq : Wk;
        int off = i & 262143;
        float4 v4 = *(const float4*)(s + off);
        ushort4 o;
        o.x = f2bf(v4.x); o.y = f2bf(v4.y); o.z = f2bf(v4.z); o.w = f2bf(v4.w);
        *(ushort4*)(Wb + i) = o;
    } else if (blk < 576) {
        const int bb = blk - 512;
        const int cp0 = (bb >> 3) * 64;
        const int c30 = (bb & 7) * 64;
        __shared__ unsigned short sT[64][65];
        #pragma unroll
        for (int i = 0; i < 4; ++i) {
            int ch = t + i * 256;
            int r = ch >> 4, col4 = (ch & 15) * 4;
            float4 v4 = *(const float4*)(Wv + (size_t)(cp0 + r) * DIMC + c30 + col4);
            sT[r][col4 + 0] = f2bf(v4.x); sT[r][col4 + 1] = f2bf(v4.y);
            sT[r][col4 + 2] = f2bf(v4.z); sT[r][col4 + 3] = f2bf(v4.w);
        }
        __syncthreads();
        #pragma unroll
        for (int i = 0; i < 2; ++i) {
            int ch = t + i * 256;
            int n = ch >> 3, cc = (ch & 7) * 8;
            Pack8 pk;
            #pragma unroll
            for (int e = 0; e < 8; ++e) pk.u[e] = sT[cc + e][n];
            *(int4*)(WvT + (size_t)(c30 + n) * DIMC + cp0 + cc) = pk.v;
        }
    } else if (blk < 832) {
        int i = ((blk - 576) * 256 + t) * 4;
        float4 v4 = *(const float4*)(Wp + i);
        ushort4 o;
        o.x = f2bf(v4.x); o.y = f2bf(v4.y); o.z = f2bf(v4.z); o.w = f2bf(v4.w);
        *(ushort4*)(Wpb + i) = o;
    } else {
        const int idx = blk - 832;
        const int n0 = (idx & 63) * 64;
        const int c0 = ((idx >> 6) & 7) * 64;
        const int b  = idx >> 9;
        __shared__ unsigned short sT[64][65];
        #pragma unroll
        for (int i = 0; i < 4; ++i) {
            int ch = t + i * 256;
            int r = ch >> 4, col4 = (ch & 15) * 4;
            float4 v4 = *(const float4*)(x + ((size_t)b * DIMC + c0 + r) * HW + n0 + col4);
            sT[r][col4 + 0] = f2bf(v4.x); sT[r][col4 + 1] = f2bf(v4.y);
            sT[r][col4 + 2] = f2bf(v4.z); sT[r][col4 + 3] = f2bf(v4.w);
            float4 mv = *(const float4*)(mask + (size_t)b * HW + n0 + col4);
            ushort4 xm;
            xm.x = f2bf(v4.x * mv.x); xm.y = f2bf(v4.y * mv.y);
            xm.z = f2bf(v4.z * mv.z); xm.w = f2bf(v4.w * mv.w);
            *(ushort4*)(xmb + ((size_t)b * DIMC + c0 + r) * HW + n0 + col4) = xm;
        }
        __syncthreads();
        #pragma unroll
        for (int i = 0; i < 2; ++i) {
            int ch = t + i * 256;
            int n = ch >> 3, cc = (ch & 7) * 8;
            Pack8 pk;
            #pragma unroll
            for (int e = 0; e < 8; ++e) pk.u[e] = sT[cc + e][n];
            *(int4*)(xT + ((size_t)b * HW + n0 + n) * DIMC + c0 + cc) = pk.v;
        }
    }
}

// ---------------------------------------------------------------------------
// K1: TRIANGULAR Gram GEMM, split-K, XCD-grouped.
// ---------------------------------------------------------------------------
__global__ __launch_bounds__(256) void gram_mfma(
    const unsigned short* __restrict__ xmb, unsigned short* __restrict__ Gpart)
{
    const int f = blockIdx.x;            // 0..319
    const int r8 = f & 7, q = f >> 3;
    const int pair = q >> 2;
    const int grp  = r8 + ((q & 3) << 3);
    const int b  = grp & 7;
    const int sp = grp >> 3;
    const int TA[10] = {0,0,0,0,1,1,1,2,2,3};
    const int TB[10] = {0,1,2,3,1,2,3,2,3,3};
    const int cA0 = TA[pair] * 128;
    const int cB0 = TB[pair] * 128;
    const unsigned short* A = xmb + (size_t)b * DIMC * HW + (size_t)cA0 * HW + sp * 1024;
    const unsigned short* B = xmb + (size_t)b * DIMC * HW + (size_t)cB0 * HW + sp * 1024;

    __shared__ __align__(16) char sm[65536];

    const int t = threadIdx.x, lane = t & 63, w = t >> 6;
    const int wm = w >> 1, wn = w & 1;
    const int rsub = lane >> 3;
    const int srccol = ((lane & 7) ^ rsub) << 3;

    f32x4 zero = {0.f, 0.f, 0.f, 0.f};
    f32x4 acc[4][4];
    #pragma unroll
    for (int m = 0; m < 4; ++m)
        #pragma unroll
        for (int n = 0; n < 4; ++n) acc[m][n] = zero;

    #define STAGE_G(buf, c0)                                                  \
        {                                                                     \
            char* dst = sm + (buf) * 32768;                                   \
            _Pragma("unroll")                                                 \
            for (int i = 0; i < 4; ++i) {                                     \
                int ii = w * 4 + i;                                           \
                gload_lds16(A + (size_t)(ii * 8 + rsub) * HW + (c0) + srccol, \
                            dst + ii * 1024);                                 \
                gload_lds16(B + (size_t)(ii * 8 + rsub) * HW + (c0) + srccol, \
                            dst + 16384 + ii * 1024);                         \
            }                                                                 \
        }

    STAGE_G(0, 0);
    int cur = 0;
    for (int c0 = 0; c0 < 1024; c0 += 64) {
        __syncthreads();
        if (c0 + 64 < 1024) STAGE_G(cur ^ 1, c0 + 64);
        const char* sA = sm + cur * 32768;
        const char* sB = sA + 16384;
        #pragma unroll
        for (int s = 0; s < 2; ++s) {
            bf16x8 af[4], bfr[4];
            #pragma unroll
            for (int m = 0; m < 4; ++m) {
                int r = wm * 64 + m * 16 + (lane & 15);
                int byte = r * 128 + s * 64 + ((lane >> 4) << 4);
                byte ^= (r & 7) << 4;
                af[m] = *(const bf16x8*)(sA + byte);
            }
            #pragma unroll
            for (int n = 0; n < 4; ++n) {
                int r = wn * 64 + n * 16 + (lane & 15);
                int byte = r * 128 + s * 64 + ((lane >> 4) << 4);
                byte ^= (r & 7) << 4;
                bfr[n] = *(const bf16x8*)(sB + byte);
            }
            #pragma unroll
            for (int m = 0; m < 4; ++m)
                #pragma unroll
                for (int n = 0; n < 4; ++n)
                    acc[m][n] = __builtin_amdgcn_mfma_f32_16x16x32_bf16(
                        af[m], bfr[n], acc[m][n], 0, 0, 0);
        }
        cur ^= 1;
    }
    #undef STAGE_G

    unsigned short* st = (unsigned short*)sm;
    __syncthreads();
    #pragma unroll
    for (int m = 0; m < 4; ++m)
        #pragma unroll
        for (int n = 0; n < 4; ++n)
            #pragma unroll
            for (int r4 = 0; r4 < 4; ++r4) {
                int jl = wm * 64 + m * 16 + ((lane >> 4) << 2) + r4;
                int nl = wn * 64 + n * 16 + (lane & 15);
                st[jl * 136 + nl] = f2bf(acc[m][n][r4]);
            }
    __syncthreads();
    unsigned short* Gp = Gpart + ((size_t)(sp * 8 + b) * 10 + pair) * 16384;
    #pragma unroll
    for (int it = 0; it < 8; ++it) {
        int idx = t + it * 256, jl = idx >> 4, l16 = idx & 15;
        int4 pv = *(int4*)((char*)sm + jl * 272 + l16 * 16);
        *(int4*)(Gp + (size_t)jl * 128 + l16 * 8) = pv;
    }
}

// ---------------------------------------------------------------------------
// K1b: reduce 4 split partials -> G, tile + transposed mirror.
// ---------------------------------------------------------------------------
__global__ __launch_bounds__(256) void gram_reduce_sym(
    const unsigned short* __restrict__ Gpart, unsigned short* __restrict__ G)
{
    const int pair = blockIdx.x;
    const int b    = blockIdx.y;
    const int TA[10] = {0,0,0,0,1,1,1,2,2,3};
    const int TB[10] = {0,1,2,3,1,2,3,2,3,3};
    const int ta = TA[pair], tb = TB[pair];
    const int t = threadIdx.x;

    __shared__ unsigned short sT[128][130];
    unsigned short* Gb = G + (size_t)b * DIMC * DIMC;

    #pragma unroll
    for (int ch = 0; ch < 8; ++ch) {
        int e = ch * 2048 + t * 8;
        int i = e >> 7, j = e & 127;
        Pack8 p0, p1, p2, p3, o;
        p0.v = *(const int4*)(Gpart + ((size_t)(0 * 8 + b) * 10 + pair) * 16384 + e);
        p1.v = *(const int4*)(Gpart + ((size_t)(1 * 8 + b) * 10 + pair) * 16384 + e);
        p2.v = *(const int4*)(Gpart + ((size_t)(2 * 8 + b) * 10 + pair) * 16384 + e);
        p3.v = *(const int4*)(Gpart + ((size_t)(3 * 8 + b) * 10 + pair) * 16384 + e);
        #pragma unroll
        for (int k = 0; k < 8; ++k) {
            unsigned short s = f2bf(bf2f(p0.u[k]) + bf2f(p1.u[k]) + bf2f(p2.u[k]) + bf2f(p3.u[k]));
            o.u[k] = s;
            sT[i][j + k] = s;
        }
        *(int4*)(Gb + (size_t)(ta * 128 + i) * DIMC + tb * 128 + j) = o.v;
    }
    if (ta != tb) {
        __syncthreads();
        #pragma unroll
        for (int ch = 0; ch < 8; ++ch) {
            int e = ch * 2048 + t * 8;
            int i2 = e >> 7, j2 = e & 127;
            Pack8 o;
            #pragma unroll
            for (int k = 0; k < 8; ++k) o.u[k] = sT[j2 + k][i2];
            *(int4*)(Gb + (size_t)(tb * 128 + i2) * DIMC + ta * 128 + j2) = o.v;
        }
    }
}

// ---------------------------------------------------------------------------
// K2: generic 128x128 NT GEMM, K=512, row stride 512, bf16 out.
// ---------------------------------------------------------------------------
__global__ __launch_bounds__(256) void gemm_nn_128(
    const unsigned short* __restrict__ Ag, size_t aBatch,
    const unsigned short* __restrict__ Bg, size_t bBatch,
    unsigned short* __restrict__ Cg, size_t cBatch)
{
    const int b  = blockIdx.z;
    const int j0 = blockIdx.y * 128;
    const int n0 = blockIdx.x * 128;
    const unsigned short* A = Ag + (size_t)b * aBatch + (size_t)j0 * DIMC;
    const unsigned short* B = Bg + (size_t)b * bBatch + (size_t)n0 * DIMC;

    __shared__ __align__(16) char sm[65536];

    const int t = threadIdx.x, lane = t & 63, w = t >> 6;
    const int wm = w >> 1, wn = w & 1;
    const int rsub = lane >> 3;
    const int srccol = ((lane & 7) ^ rsub) << 3;

    f32x4 zero = {0.f, 0.f, 0.f, 0.f};
    f32x4 acc[4][4];
    #pragma unroll
    for (int m = 0; m < 4; ++m)
        #pragma unroll
        for (int n = 0; n < 4; ++n) acc[m][n] = zero;

    #define STAGE_NN(buf, c0)                                                   \
        {                                                                       \
            char* dst = sm + (buf) * 32768;                                     \
            _Pragma("unroll")                                                   \
            for (int i = 0; i < 4; ++i) {                                       \
                int ii = w * 4 + i;                                             \
                gload_lds16(A + (size_t)(ii * 8 + rsub) * DIMC + (c0) + srccol, \
                            dst + ii * 1024);                                   \
                gload_lds16(B + (size_t)(ii * 8 + rsub) * DIMC + (c0) + srccol, \
                            dst + 16384 + ii * 1024);                           \
            }                                                                   \
        }

    STAGE_NN(0, 0);
    int cur = 0;
    for (int c0 = 0; c0 < DIMC; c0 += 64) {
        __syncthreads();
        if (c0 + 64 < DIMC) STAGE_NN(cur ^ 1, c0 + 64);
        const char* sA = sm + cur * 32768;
        const char* sB = sA + 16384;
        #pragma unroll
        for (int s = 0; s < 2; ++s) {
            bf16x8 af[4], bfr[4];
            #pragma unroll
            for (int m = 0; m < 4; ++m) {
                int r = wm * 64 + m * 16 + (lane & 15);
                int byte = r * 128 + s * 64 + ((lane >> 4) << 4);
                byte ^= (r & 7) << 4;
                af[m] = *(const bf16x8*)(sA + byte);
            }
            #pragma unroll
            for (int n = 0; n < 4; ++n) {
                int r = wn * 64 + n * 16 + (lane & 15);
                int byte = r * 128 + s * 64 + ((lane >> 4) << 4);
                byte ^= (r & 7) << 4;
                bfr[n] = *(const bf16x8*)(sB + byte);
            }
            #pragma unroll
            for (int m = 0; m < 4; ++m)
                #pragma unroll
                for (int n = 0; n < 4; ++n)
                    acc[m][n] = __builtin_amdgcn_mfma_f32_16x16x32_bf16(
                        af[m], bfr[n], acc[m][n], 0, 0, 0);
        }
        cur ^= 1;
    }
    #undef STAGE_NN

    unsigned short* st = (unsigned short*)sm;
    __syncthreads();
    #pragma unroll
    for (int m = 0; m < 4; ++m)
        #pragma unroll
        for (int n = 0; n < 4; ++n)
            #pragma unroll
            for (int r4 = 0; r4 < 4; ++r4) {
                int jl = wm * 64 + m * 16 + ((lane >> 4) << 2) + r4;
                int nl = wn * 64 + n * 16 + (lane & 15);
                st[jl * 136 + nl] = f2bf(acc[m][n][r4]);
            }
    __syncthreads();
    #pragma unroll
    for (int it = 0; it < 8; ++it) {
        int idx = t + it * 256, jl = idx >> 4, l16 = idx & 15;
        int4 pv = *(int4*)((char*)sm + jl * 272 + l16 * 16);
        *(int4*)(Cg + (size_t)b * cBatch + (size_t)(j0 + jl) * DIMC + n0 + l16 * 8) = pv;
    }
}

// ---------------------------------------------------------------------------
// K4: fused rsq + S + softmax per (b,h); emits attnT bf16 [b][h][d][c].
// ---------------------------------------------------------------------------
__global__ __launch_bounds__(256) void s_softmax(
    const unsigned short* __restrict__ TU, const unsigned short* __restrict__ Wb,
    unsigned short* __restrict__ attnT)
{
    const int bh = blockIdx.x;
    const int b = bh >> 3, h = bh & 7;
    const unsigned short* A = TU + ((size_t)b * 1024 + h * 64) * DIMC;
    const unsigned short* B = Wb + 262144 + (size_t)(h * 64) * DIMC;

    __shared__ __align__(16) char sm[32768];
    __shared__ float sS[64][65];
    __shared__ float srq[64];
    __shared__ float srk[64];
    __shared__ unsigned short aT[64][65];

    const int t = threadIdx.x, lane = t & 63, w = t >> 6;
    const int wm = w >> 1, wn = w & 1;
    const int rsub = lane >> 3;
    const int srccol = ((lane & 7) ^ rsub) << 3;

    {
        const int rid  = t >> 1;
        const int half = t & 1;
        const int isK  = (rid >= 64);
        const int rl   = rid & 63;
        const unsigned short* ar = TU + ((size_t)b * 1024 + (isK ? 512 : 0) + h * 64 + rl) * DIMC
                                 + half * 256;
        const unsigned short* wr = Wb + (isK ? 262144 : 0) + (size_t)(h * 64 + rl) * DIMC
                                 + half * 256;
        float s = 0.f;
        #pragma unroll 8
        for (int i = 0; i < 32; ++i) {
            Pack8 pa, pw;
            pa.v = *(const int4*)(ar + i * 8);
            pw.v = *(const int4*)(wr + i * 8);
            #pragma unroll
            for (int e = 0; e < 8; ++e) s = fmaf(bf2f(pa.u[e]), bf2f(pw.u[e]), s);
        }
        s += __shfl_xor(s, 1, 2);
        if (half == 0) {
            float r = 1.0f / fmaxf(sqrtf(s), EPSN);
            if (isK) srk[rl] = r; else srq[rl] = r;
        }
    }

    f32x4 zero = {0.f, 0.f, 0.f, 0.f};
    f32x4 acc[2][2];
    #pragma unroll
    for (int m = 0; m < 2; ++m)
        #pragma unroll
        for (int n = 0; n < 2; ++n) acc[m][n] = zero;

    #define STAGE_S(buf, c0)                                                    \
        {                                                                       \
            char* dst = sm + (buf) * 16384;                                     \
            _Pragma("unroll")                                                   \
            for (int i = 0; i < 2; ++i) {                                       \
                int ii = w * 2 + i;                                             \
                gload_lds16(A + (size_t)(ii * 8 + rsub) * DIMC + (c0) + srccol, \
                            dst + ii * 1024);                                   \
                gload_lds16(B + (size_t)(ii * 8 + rsub) * DIMC + (c0) + srccol, \
                            dst + 8192 + ii * 1024);                            \
            }                                                                   \
        }

    STAGE_S(0, 0);
    int cur = 0;
    for (int c0 = 0; c0 < DIMC; c0 += 64) {
        __syncthreads();
        if (c0 + 64 < DIMC) STAGE_S(cur ^ 1, c0 + 64);
        const char* sA = sm + cur * 16384;
        const char* sB = sA + 8192;
        #pragma unroll
        for (int s = 0; s < 2; ++s) {
            bf16x8 aq[2], bk[2];
            #pragma unroll
            for (int m = 0; m < 2; ++m) {
                int r = wm * 32 + m * 16 + (lane & 15);
                int byte = r * 128 + s * 64 + ((lane >> 4) << 4);
                byte ^= (r & 7) << 4;
                aq[m] = *(const bf16x8*)(sA + byte);
            }
            #pragma unroll
            for (int n = 0; n < 2; ++n) {
                int r = wn * 32 + n * 16 + (lane & 15);
                int byte = r * 128 + s * 64 + ((lane >> 4) << 4);
                byte ^= (r & 7) << 4;
                bk[n] = *(const bf16x8*)(sB + byte);
            }
            #pragma unroll
            for (int m = 0; m < 2; ++m)
                #pragma unroll
                for (int n = 0; n < 2; ++n)
                    acc[m][n] = __builtin_amdgcn_mfma_f32_16x16x32_bf16(
                        aq[m], bk[n], acc[m][n], 0, 0, 0);
        }
        cur ^= 1;
    }
    #undef STAGE_S

    #pragma unroll
    for (int m = 0; m < 2; ++m)
        #pragma unroll
        for (int n = 0; n < 2; ++n)
            #pragma unroll
            for (int r4 = 0; r4 < 4; ++r4) {
                int r = wm * 32 + m * 16 + ((lane >> 4) << 2) + r4;
                int c = wn * 32 + n * 16 + (lane & 15);
                sS[r][c] = acc[m][n][r4];
            }
    __syncthreads();

    const int r = t >> 2;
    const int p = t & 3;
    const float rq = srq[r];
    float row[16];
    #pragma unroll
    for (int c = 0; c < 16; ++c)
        row[c] = sS[r][p * 16 + c] * SCALE * rq * srk[p * 16 + c];
    float mx = row[0];
    #pragma unroll
    for (int c = 1; c < 16; ++c) mx = fmaxf(mx, row[c]);
    mx = fmaxf(mx, __shfl_xor(mx, 1, 4));
    mx = fmaxf(mx, __shfl_xor(mx, 2, 4));
    float sum = 0.f;
    #pragma unroll
    for (int c = 0; c < 16; ++c) { row[c] = __expf(row[c] - mx); sum += row[c]; }
    sum += __shfl_xor(sum, 1, 4);
    sum += __shfl_xor(sum, 2, 4);
    const float inv = 1.0f / sum;
    #pragma unroll
    for (int i = 0; i < 16; ++i)
        aT[p * 16 + i][r] = f2bf(row[i] * inv);
    __syncthreads();
    {
        const int d  = t >> 2;
        const int ch = t & 3;
        Pack8 o0, o1;
        #pragma unroll
        for (int e = 0; e < 8; ++e) { o0.u[e] = aT[d][ch * 16 + e]; o1.u[e] = aT[d][ch * 16 + 8 + e]; }
        unsigned short* dst = attnT + (((size_t)bh * 64) + d) * 64 + ch * 16;
        *(int4*)(dst)     = o0.v;
        *(int4*)(dst + 8) = o1.v;
    }
}

// ---------------------------------------------------------------------------
// K5: Wp2 via MFMA. Wp2[b][j][h*64+d] = sum_c Wpb[j][h*64+c]*attnT[bh][d][c]
// ---------------------------------------------------------------------------
__global__ __launch_bounds__(256) void wp2_mfma(
    const unsigned short* __restrict__ Wpb, const unsigned short* __restrict__ attnT,
    unsigned short* __restrict__ Wp2b)
{
    const int j0 = blockIdx.x * 128;
    const int h  = blockIdx.y;
    const int b  = blockIdx.z;
    const unsigned short* A = Wpb + (size_t)j0 * DIMC + h * 64;
    const unsigned short* B = attnT + (size_t)(b * 8 + h) * 4096;

    __shared__ __align__(16) char sm[24576];

    const int t = threadIdx.x, lane = t & 63, w = t >> 6;
    const int rsub = lane >> 3;
    const int srccol = ((lane & 7) ^ rsub) << 3;

    #pragma unroll
    for (int i = 0; i < 4; ++i) {
        int ii = w * 4 + i;
        gload_lds16(A + (size_t)(ii * 8 + rsub) * DIMC + srccol, sm + ii * 1024);
    }
    #pragma unroll
    for (int i = 0; i < 2; ++i) {
        int ii = w * 2 + i;
        gload_lds16(B + (size_t)(ii * 8 + rsub) * 64 + srccol, sm + 16384 + ii * 1024);
    }
    __syncthreads();

    f32x4 zero = {0.f, 0.f, 0.f, 0.f};
    f32x4 acc[2][4];
    #pragma unroll
    for (int m = 0; m < 2; ++m)
        #pragma unroll
        for (int n = 0; n < 4; ++n) acc[m][n] = zero;

    #pragma unroll
    for (int s = 0; s < 2; ++s) {
        bf16x8 af[2], bfr[4];
        #pragma unroll
        for (int m = 0; m < 2; ++m) {
            int r = w * 32 + m * 16 + (lane & 15);
            int byte = r * 128 + s * 64 + ((lane >> 4) << 4);
            byte ^= (r & 7) << 4;
            af[m] = *(const bf16x8*)(sm + byte);
        }
        #pragma unroll
        for (int n = 0; n < 4; ++n) {
            int r = n * 16 + (lane & 15);
            int byte = r * 128 + s * 64 + ((lane >> 4) << 4);
            byte ^= (r & 7) << 4;
            bfr[n] = *(const bf16x8*)(sm + 16384 + byte);
        }
        #pragma unroll
        for (int m = 0; m < 2; ++m)
            #pragma unroll
            for (int n = 0; n < 4; ++n)
                acc[m][n] = __builtin_amdgcn_mfma_f32_16x16x32_bf16(
                    af[m], bfr[n], acc[m][n], 0, 0, 0);
    }

    unsigned short* st = (unsigned short*)sm;
    __syncthreads();
    #pragma unroll
    for (int m = 0; m < 2; ++m)
        #pragma unroll
        for (int n = 0; n < 4; ++n)
            #pragma unroll
            for (int r4 = 0; r4 < 4; ++r4) {
                int jl = w * 32 + m * 16 + ((lane >> 4) << 2) + r4;
                int dl = n * 16 + (lane & 15);
                st[jl * 72 + dl] = f2bf(acc[m][n][r4]);
            }
    __syncthreads();
    #pragma unroll
    for (int it = 0; it < 4; ++it) {
        int idx = t + it * 256, jl = idx >> 3, ch = idx & 7;
        int4 pv = *(int4*)((char*)sm + jl * 144 + ch * 16);
        *(int4*)(Wp2b + ((size_t)b * DIMC + j0 + jl) * DIMC + h * 64 + ch * 8) = pv;
    }
}

// ---------------------------------------------------------------------------
// K6: final GEMM, XCD-grouped: out[b][j][n] = sum_c3 Wfb[j][c3]*xT[n][c3]
// ---------------------------------------------------------------------------
__global__ __launch_bounds__(256) void final_mfma(
    const unsigned short* __restrict__ Wfb, const unsigned short* __restrict__ xT,
    float* __restrict__ out)
{
    const int f = blockIdx.x;            // 0..1023
    const int r8 = f & 7, q = f >> 3;
    const int jt = q & 3;
    const int nt = r8 + (((q >> 2) & 3) << 3);
    const int b  = q >> 4;
    const int j0 = jt * 128;
    const int n0 = nt * 128;
    const unsigned short* A = Wfb + (size_t)b * DIMC * DIMC + (size_t)j0 * DIMC;
    const unsigned short* B = xT + (size_t)b * HW * DIMC + (size_t)n0 * DIMC;

    __shared__ __align__(16) char sm[65536];

    const int t = threadIdx.x, lane = t & 63, w = t >> 6;
    const int wm = w >> 1, wn = w & 1;
    const int rsub = lane >> 3;
    const int srccol = ((lane & 7) ^ rsub) << 3;

    f32x4 zero = {0.f, 0.f, 0.f, 0.f};
    f32x4 acc[4][4];
    #pragma unroll
    for (int m = 0; m < 4; ++m)
        #pragma unroll
        for (int n = 0; n < 4; ++n) acc[m][n] = zero;

    #define STAGE_FIN(buf, c0)                                                  \
        {                                                                       \
            char* dst = sm + (buf) * 32768;                                     \
            _Pragma("unroll")                                                   \
            for (int i = 0; i < 4; ++i) {                                       \
                int ii = w * 4 + i;                                             \
                gload_lds16(A + (size_t)(ii * 8 + rsub) * DIMC + (c0) + srccol, \
                            dst + ii * 1024);                                   \
                gload_lds16(B + (size_t)(ii * 8 + rsub) * DIMC + (c0) + srccol, \
                            dst + 16384 + ii * 1024);                           \
            }                                                                   \
        }

    STAGE_FIN(0, 0);
    int cur = 0;
    for (int c0 = 0; c0 < DIMC; c0 += 64) {
        __syncthreads();
        if (c0 + 64 < DIMC) STAGE_FIN(cur ^ 1, c0 + 64);
        const char* sA = sm + cur * 32768;
        const char* sB = sA + 16384;
        #pragma unroll
        for (int s = 0; s < 2; ++s) {
            bf16x8 af[4], bfr[4];
            #pragma unroll
            for (int m = 0; m < 4; ++m) {
                int r = wm * 64 + m * 16 + (lane & 15);
                int byte = r * 128 + s * 64 + ((lane >> 4) << 4);
                byte ^= (r & 7) << 4;
                af[m] = *(const bf16x8*)(sA + byte);
            }
            #pragma unroll
            for (int n = 0; n < 4; ++n) {
                int r = wn * 64 + n * 16 + (lane & 15);
                int byte = r * 128 + s * 64 + ((lane >> 4) << 4);
                byte ^= (r & 7) << 4;
                bfr[n] = *(const bf16x8*)(sB + byte);
            }
            #pragma unroll
            for (int m = 0; m < 4; ++m)
                #pragma unroll
                for (int n = 0; n < 4; ++n)
                    acc[m][n] = __builtin_amdgcn_mfma_f32_16x16x32_bf16(
                        af[m], bfr[n], acc[m][n], 0, 0, 0);
        }
        cur ^= 1;
    }
    #undef STAGE_FIN

    #pragma unroll
    for (int m = 0; m < 4; ++m)
        #pragma unroll
        for (int r4 = 0; r4 < 4; ++r4) {
            int j = j0 + wm * 64 + m * 16 + ((lane >> 4) << 2) + r4;
            size_t rowbase = ((size_t)b * DIMC + j) * HW + n0 + wn * 64 + (lane & 15);
            #pragma unroll
            for (int n = 0; n < 4; ++n)
                out[rowbase + n * 16] = acc[m][n][r4];
        }
}

// ---------------------------------------------------------------------------
// Workspace (bytes):
//   xT    @ 0           67,108,864
//   xmb   @ 67108864    67,108,864
//   Wb    @ 134217728    1,048,576
//   WvT   @ 135266304      524,288
//   Wpb   @ 135790592      524,288
//   G     @ 136314880    4,194,304
//   TU    @ 140509184    8,388,608
//   attnT @ 148897792      524,288
//   Wp2b  @ 149422080    4,194,304
//   Wfb   @ 153616384    4,194,304
//   Gpart @ 157810688   10,485,760
// ---------------------------------------------------------------------------
extern "C" void kernel_launch(void* const* d_in, const int* in_sizes, int n_in,
                              void* d_out, int out_size, void* d_ws, size_t ws_size,
                              hipStream_t stream)
{
    const float* x    = (const float*)d_in[0];
    const float* mask = (const float*)d_in[1];
    const float* Wq   = (const float*)d_in[2];
    const float* Wk   = (const float*)d_in[3];
    const float* Wv   = (const float*)d_in[4];
    const float* Wp   = (const float*)d_in[5];
    float* out = (float*)d_out;
    char* wsb = (char*)d_ws;

    unsigned short* xT   = (unsigned short*)(wsb + 0);
    unsigned short* xmb  = (unsigned short*)(wsb + 67108864);
    unsigned short* Wb   = (unsigned short*)(wsb + 134217728);
    unsigned short* WvT  = (unsigned short*)(wsb + 135266304);
    unsigned short* Wpb  = (unsigned short*)(wsb + 135790592);
    unsigned short* G    = (unsigned short*)(wsb + 136314880);
    unsigned short* TU   = (unsigned short*)(wsb + 140509184);
    unsigned short* attnT= (unsigned short*)(wsb + 148897792);
    unsigned short* Wp2b = (unsigned short*)(wsb + 149422080);
    unsigned short* Wfb  = (unsigned short*)(wsb + 153616384);
    unsigned short* Gpart= (unsigned short*)(wsb + 157810688);

    prep_wx        <<<4928,            256, 0, stream>>>(Wq, Wk, Wv, Wp, x, mask,
                                                         Wb, WvT, Wpb, xT, xmb);
    gram_mfma      <<<320,             256, 0, stream>>>(xmb, Gpart);
    gram_reduce_sym<<<dim3(10, 8),     256, 0, stream>>>(Gpart, G);
    gemm_nn_128    <<<dim3(4, 8, 8),   256, 0, stream>>>(Wb, (size_t)0, G, (size_t)(DIMC*DIMC), TU, (size_t)(1024*DIMC));
    s_softmax      <<<64,              256, 0, stream>>>(TU, Wb, attnT);
    wp2_mfma       <<<dim3(4, 8, 8),   256, 0, stream>>>(Wpb, attnT, Wp2b);
    gemm_nn_128    <<<dim3(4, 4, 8),   256, 0, stream>>>(Wp2b, (size_t)(DIMC*DIMC), WvT, (size_t)0, Wfb, (size_t)(DIMC*DIMC));
    final_mfma     <<<1024,            256, 0, stream>>>(Wfb, xT, out);
}